// Round 10
// baseline (127.812 us; speedup 1.0000x reference)
//
#include <hip/hip_runtime.h>
#include <hip/hip_bf16.h>
#include <hip/hip_fp16.h>

// Problem constants
#define BATCH 256
#define IN_DIM 1024
#define NKER 100
#define DKER 50
#define ACT_N 5000           // NKER*DKER
#define OUT_DIM 1124         // IN_DIM + NKER

typedef short bf16x8 __attribute__((ext_vector_type(8)));
typedef short bf16x4 __attribute__((ext_vector_type(4)));
typedef float f32x4v __attribute__((ext_vector_type(4)));
typedef _Float16 h2 __attribute__((ext_vector_type(2)));

// ============ Kernel 1: bf16 MFMA GEMM  act = x @ W  (fp32 in, fp16 out) ============
// Tile 64M x 64N, BK=128, grid 320 (316 active, XCD-swizzled), 256 thr (4 waves
// in 2x2, wave tile 32x32 -> frag-read:MFMA ratio 1:1).
// Staging loads are INLINE-ASM global_load_dwordx4: issue point pinned (volatile
// asm cannot sink past barriers like R2-R8's C loads, which rocprof showed
// draining through a ~36-VGPR window = serialized latency). All 16 loads/thread
// stay in flight across the MFMA phase. Data dependence after the drain is
// expressed with per-SCALAR "+v" laundering (tied 128-bit tuples are
// unsupported -> R9 compile failure).
#define LDSB 136   // bf16 row stride (272 B): frag b128 reads conflict-free

#define GL4(dst, p) asm volatile("global_load_dwordx4 %0, %1, off" : "=v"(dst) : "v"(p))
#define LAUNDER8(v0, v1) asm volatile(""                                         \
    : "+v"(v0.x), "+v"(v0.y), "+v"(v0.z), "+v"(v0.w),                            \
      "+v"(v1.x), "+v"(v1.y), "+v"(v1.z), "+v"(v1.w))

__global__ __launch_bounds__(256, 2) void gemm_bf16_kernel(const float* __restrict__ X,
                                                           const float* __restrict__ W,
                                                           __half* __restrict__ act) {
    __shared__ __attribute__((aligned(16))) __hip_bfloat16 A_lds[64 * LDSB];
    __shared__ __attribute__((aligned(16))) __hip_bfloat16 B_lds[64 * LDSB];

    const int t = threadIdx.x, lane = t & 63, w = t >> 6;
    const int fl = lane & 15, fq = lane >> 4;
    // XCD swizzle: 4 m-blocks sharing one W column-slice -> same XCD -> L2 reuse.
    const int id = blockIdx.x;                     // 0..319 (4 idle)
    const int nb = (id & 7) + (id >> 5) * 8;       // 0..79
    const int mb = (id >> 3) & 3;                  // 0..3
    if (nb >= 79) return;
    const int m0 = mb * 64, n0 = nb * 64;

    // A staging map: thread -> row (t>>2), 32-float k-seg ((t&3)*32), 8 dwordx4
    const int arow = t >> 2, aseg = (t & 3) * 32;
    const float* aP = X + (m0 + arow) * IN_DIM + aseg;
    // B staging map: thread -> n-quad (t&15), k-base 4*(t>>4); 8 dwordx4 = 4n x {kb..kb+3, kb+64..kb+67}
    const int nq = t & 15, kb = (t >> 4) * 4;
    const int ncol = n0 + nq * 4;
    const bool bok = (ncol + 3) < ACT_N;
    const float* bP = bok ? (W + (size_t)kb * ACT_N + ncol) : W;  // dummy stays in-bounds

    const int wm = (w & 1) * 32, wn = (w >> 1) * 32;
    f32x4v acc[2][2] = {};

    float4 La0, La1, La2, La3, La4, La5, La6, La7;
    float4 Lb0, Lb1, Lb2, Lb3, Lb4, Lb5, Lb6, Lb7;

#define ISSUE(IT) {                                                              \
    const float* ap = aP + (IT) * 128;                                           \
    GL4(La0, ap + 0);  GL4(La1, ap + 4);  GL4(La2, ap + 8);  GL4(La3, ap + 12);  \
    GL4(La4, ap + 16); GL4(La5, ap + 20); GL4(La6, ap + 24); GL4(La7, ap + 28);  \
    const float* bp = bP + (size_t)(IT) * 128 * ACT_N;                           \
    GL4(Lb0, bp + (size_t)0 * ACT_N);  GL4(Lb1, bp + (size_t)1 * ACT_N);         \
    GL4(Lb2, bp + (size_t)2 * ACT_N);  GL4(Lb3, bp + (size_t)3 * ACT_N);         \
    GL4(Lb4, bp + (size_t)64 * ACT_N); GL4(Lb5, bp + (size_t)65 * ACT_N);        \
    GL4(Lb6, bp + (size_t)66 * ACT_N); GL4(Lb7, bp + (size_t)67 * ACT_N); }

#define REFRESH16() {                                                            \
    asm volatile("s_waitcnt vmcnt(0)" ::: "memory");                             \
    LAUNDER8(La0, La1); LAUNDER8(La2, La3);                                      \
    LAUNDER8(La4, La5); LAUNDER8(La6, La7);                                      \
    LAUNDER8(Lb0, Lb1); LAUNDER8(Lb2, Lb3);                                      \
    LAUNDER8(Lb4, Lb5); LAUNDER8(Lb6, Lb7); }

#define STAGE_WRITE() {                                                          \
    const float4 AA[8] = {La0, La1, La2, La3, La4, La5, La6, La7};               \
    _Pragma("unroll")                                                            \
    for (int q = 0; q < 4; ++q) {                                                \
        __hip_bfloat16 tm[8];                                                    \
        const float* p0 = (const float*)&AA[2 * q];                              \
        _Pragma("unroll")                                                        \
        for (int e = 0; e < 8; ++e) tm[e] = __float2bfloat16(p0[e]);             \
        *(bf16x8*)&A_lds[arow * LDSB + aseg + q * 8] = *(const bf16x8*)tm;       \
    }                                                                            \
    const float4 BB[8] = {Lb0, Lb1, Lb2, Lb3, Lb4, Lb5, Lb6, Lb7};               \
    _Pragma("unroll")                                                            \
    for (int r = 0; r < 2; ++r) {                                                \
        _Pragma("unroll")                                                        \
        for (int j = 0; j < 4; ++j) {                                            \
            __hip_bfloat16 tb[4];                                                \
            tb[0] = __float2bfloat16(((const float*)&BB[r * 4 + 0])[j]);         \
            tb[1] = __float2bfloat16(((const float*)&BB[r * 4 + 1])[j]);         \
            tb[2] = __float2bfloat16(((const float*)&BB[r * 4 + 2])[j]);         \
            tb[3] = __float2bfloat16(((const float*)&BB[r * 4 + 3])[j]);         \
            *(bf16x4*)&B_lds[(nq * 4 + j) * LDSB + kb + r * 64] = *(const bf16x4*)tb; \
        }                                                                        \
    } }

    // ---- prologue: stage k-tile 0 ----
    ISSUE(0);
    REFRESH16();
    STAGE_WRITE();
    __syncthreads();

    for (int it = 0; it < 8; ++it) {
        if (it < 7) ISSUE(it + 1);          // in flight across the MFMA phase

        #pragma unroll
        for (int kq = 0; kq < 4; ++kq) {
            bf16x8 af0 = *(const bf16x8*)&A_lds[(wm +      fl) * LDSB + kq * 32 + fq * 8];
            bf16x8 af1 = *(const bf16x8*)&A_lds[(wm + 16 + fl) * LDSB + kq * 32 + fq * 8];
            bf16x8 bf0 = *(const bf16x8*)&B_lds[(wn +      fl) * LDSB + kq * 32 + fq * 8];
            bf16x8 bf1 = *(const bf16x8*)&B_lds[(wn + 16 + fl) * LDSB + kq * 32 + fq * 8];
            acc[0][0] = __builtin_amdgcn_mfma_f32_16x16x32_bf16(af0, bf0, acc[0][0], 0, 0, 0);
            acc[0][1] = __builtin_amdgcn_mfma_f32_16x16x32_bf16(af0, bf1, acc[0][1], 0, 0, 0);
            acc[1][0] = __builtin_amdgcn_mfma_f32_16x16x32_bf16(af1, bf0, acc[1][0], 0, 0, 0);
            acc[1][1] = __builtin_amdgcn_mfma_f32_16x16x32_bf16(af1, bf1, acc[1][1], 0, 0, 0);
        }
        __syncthreads();                    // all waves done reading LDS tile `it`
        if (it < 7) {
            REFRESH16();                    // wait + launder: cvts below must use loaded data
            STAGE_WRITE();
            __syncthreads();
        }
    }

    // ---- epilogue: C/D layout col = lane&15, row = (lane>>4)*4 + reg ----
    #pragma unroll
    for (int mt = 0; mt < 2; ++mt) {
        const int row0 = m0 + wm + mt * 16 + fq * 4;
        #pragma unroll
        for (int nt = 0; nt < 2; ++nt) {
            const int col = n0 + wn + nt * 16 + fl;
            if (col < ACT_N) {
                #pragma unroll
                for (int r = 0; r < 4; ++r)
                    act[(row0 + r) * ACT_N + col] = __float2half(acc[mt][nt][r]);
            }
        }
    }
}

// ============ Kernel 2: FUSED pairwise + feature write + x-copy (unchanged R8) ============
#define PKACC(r, m, acc) { h2 dd = __builtin_bit_cast(h2, (uint)(m)) - __builtin_bit_cast(h2, (uint)(r)); \
    uint uu = __builtin_bit_cast(uint, dd) & 0x7FFF7FFFu;                                                \
    acc = acc + __builtin_bit_cast(h2, uu); }

__global__ __launch_bounds__(512) void pairwise_kernel(const __half* __restrict__ act,
                                                       const float* __restrict__ x,
                                                       float* __restrict__ out) {
    const int k  = blockIdx.x;
    const int ib = blockIdx.y * 128;
    __shared__ __attribute__((aligned(16))) __half S[256 * 56];
    __shared__ float P[8 * 128];
    const int tid = threadIdx.x;

    const ushort* __restrict__ src = (const ushort*)act + k * DKER;
    for (int idx = tid; idx < 256 * 32; idx += 512) {
        const int j = idx >> 5, d = idx & 31;
        if (d < 28) {
            uint v = 0u;
            if (d < 25) v = *(const uint*)(src + j * ACT_N + d * 2);
            *(uint*)&S[j * 56 + d * 2] = v;
        }
    }

    if (k < 64) {
        const int row = ib + k * 2 + (tid >> 8);
        const int c4  = tid & 255;
        *(float4*)&out[row * OUT_DIM + c4 * 4] = *(const float4*)&x[row * IN_DIM + c4 * 4];
    }
    __syncthreads();

    const int lane = tid & 63, w = tid >> 6;

    uint my1[28], my2[28];
    {
        const uint* r1 = (const uint*)&S[(ib + lane) * 56];
        const uint* r2 = (const uint*)&S[(ib + 64 + lane) * 56];
        #pragma unroll
        for (int d = 0; d < 28; ++d) { my1[d] = r1[d]; my2[d] = r2[d]; }
    }

    const h2 kOne = { (_Float16)1.0f, (_Float16)1.0f };
    float sA = 0.f, sB = 0.f;
    const int j0 = w * 32;
    for (int jj = 0; jj < 32; ++jj) {
        const uint4* row4 = (const uint4*)&S[(j0 + jj) * 56];
        h2 cA0 = {0, 0}, cA1 = {0, 0}, cB0 = {0, 0}, cB1 = {0, 0};
        #pragma unroll
        for (int q = 0; q < 7; ++q) {
            const uint4 rv = row4[q];
            PKACC(rv.x, my1[4*q+0], cA0) PKACC(rv.y, my1[4*q+1], cA1)
            PKACC(rv.z, my1[4*q+2], cA0) PKACC(rv.w, my1[4*q+3], cA1)
            PKACC(rv.x, my2[4*q+0], cB0) PKACC(rv.y, my2[4*q+1], cB1)
            PKACC(rv.z, my2[4*q+2], cB0) PKACC(rv.w, my2[4*q+3], cB1)
        }
        const float l1A = __builtin_amdgcn_fdot2(cA0 + cA1, kOne, 0.f, false);
        const float l1B = __builtin_amdgcn_fdot2(cB0 + cB1, kOne, 0.f, false);
        sA += __expf(-l1A);
        sB += __expf(-l1B);
    }

    P[w * 128 + lane]      = sA;
    P[w * 128 + 64 + lane] = sB;
    __syncthreads();
    if (tid < 128) {
        float f = 0.f;
        #pragma unroll
        for (int g = 0; g < 8; ++g) f += P[g * 128 + tid];
        out[(ib + tid) * OUT_DIM + IN_DIM + k] = f;
    }
}

extern "C" void kernel_launch(void* const* d_in, const int* in_sizes, int n_in,
                              void* d_out, int out_size, void* d_ws, size_t ws_size,
                              hipStream_t stream) {
    const float* x = (const float*)d_in[0];       // 256x1024
    const float* w = (const float*)d_in[1];       // 1024x5000
    float* out = (float*)d_out;                   // 256x1124
    __half* act = (__half*)d_ws;                  // 256x5000 fp16 (2.56 MB)

    gemm_bf16_kernel<<<dim3(320), dim3(256), 0, stream>>>(x, w, act);
    pairwise_kernel<<<dim3(NKER, 2), dim3(512), 0, stream>>>(act, x, out);
}